// Round 1
// baseline (341.527 us; speedup 1.0000x reference)
//
#include <hip/hip_runtime.h>

// DeepNovo intensity-window gather, round 6.
// R5 (LDS fp16 spectrum, 640thr/520act, 2 blk/CU) = ~122us kernel (2.2 TB/s
// store vs 6.3 achievable). Counter arithmetic: VALU ~11%, LDS ~35%, HBM-wr
// ~35% -> latency-bound at 20 waves/CU, capped by the 60KB LDS spectrum.
// R6: drop LDS entirely. Spectrum (120KB fp32) is L2-resident -> gather via
// global_load_dword. BLOCK=256, GRID=2015 (515840 threads = 992*520) so the
// per-thread column is loop-invariant (all j-decode hoisted) and row walks
// +992/iter. VGPR<=64 via launch_bounds -> 8 blk/CU = 32 waves/CU. Stores
// stay nontemporal float4, fully coalesced (1KB/wave). fp32 gathers also
// remove the fp16 quantization error (absmax ~0 expected).

#define MASS_H2O 18.01056f
#define MASS_NH3 17.02655f

typedef float floatx4 __attribute__((ext_vector_type(4)));

constexpr int MAX_MZ = 30000;
constexpr int WIN = 10;
constexpr int CPR = 26 * 20;              // 520 float4 chunks per batch row
constexpr int BLOCK = 256;
constexpr int GRID = 2015;                // 2015*256 = 515840 = 520*992
constexpr int THREADS = GRID * BLOCK;     // stride, ≡ 0 (mod 520)
constexpr int ROW_STEP = THREADS / CPR;   // 992 rows per k-step

__global__ __launch_bounds__(BLOCK, 8) void intensity_kernel(
    const float* __restrict__ spectrum,
    const float* __restrict__ pepmass,
    const float* __restrict__ prefix_mass,
    const float* __restrict__ masses,
    const int*   __restrict__ dir_p,
    float* __restrict__ out,
    int batch)
{
    const int tid = (int)blockIdx.x * BLOCK + (int)threadIdx.x;
    const long long total = (long long)batch * CPR;     // total float4 chunks
    // iterations for this thread: ceil((total - tid) / THREADS)
    const int n = (int)((total - (long long)tid + (THREADS - 1)) / THREADS);

    // ---- loop-invariant decode (column is invariant: stride % 520 == 0) ----
    const int col  = tid % CPR;
    const int row0 = tid / CPR;
    const int v = col / 20;
    const int q = col - v * 20;
    const float ms = masses[v];
    const float lm = (v > 2) ? 1.0f : 0.0f;
    const int dir = dir_p[0];

    bool  scy[4];     // ion is a y-ion (base = cy)
    float aj[4];      // additive term (-H2O / -NH3 / 0)
    float mj10[4];    // mulj * 10  (5 for ++ ions, else 10) -- exact vs ref
    int   wj[4];      // window position 0..9
#pragma unroll
    for (int j = 0; j < 4; ++j) {
        int e   = 4 * q + j;
        int ion = e / 10;
        wj[j]  = e - ion * 10;
        scy[j] = (ion >= 4);
        int kk = ion & 3;
        aj[j]   = (kk == 1) ? -MASS_H2O : (kk == 2) ? -MASS_NH3 : 0.0f;
        mj10[j] = (kk == 3) ? 5.0f : 10.0f;
    }

    const float* pm_p = pepmass + row0;
    const float* pf_p = prefix_mass + row0;
    floatx4* op = reinterpret_cast<floatx4*>(out) + tid;

#pragma unroll 4
    for (int k = 0; k < n; ++k) {
        // lanes of a wave span at most 2 rows -> 1-2 cache lines, L2-resident
        float pm = pm_p[k * ROW_STEP];
        float pf = pf_p[k * ROW_STEP];
        float t = pf + ms;          // cb (dir==0), exact ref arithmetic
        float u = pm - t;           // cy (dir==0)
        float cb = (dir == 0) ? t : u;
        float cy = (dir == 0) ? u : t;

        float vals[4];
#pragma unroll
        for (int j = 0; j < 4; ++j) {
            float base = scy[j] ? cy : cb;              // true select: bit-exact
            float f = (base + aj[j]) * mj10[j];         // == ref rounding (x*.5 exact)
            int idx = (int)rintf(f) - (WIN / 2);        // v_rndne + v_cvt_i32
            bool valid = (unsigned)idx <= (unsigned)(MAX_MZ - WIN);
            int ga = (valid ? idx : 0) + wj[j];         // <= 29999: in bounds
            float s = spectrum[ga];                     // L2-resident gather
            vals[j] = valid ? s * lm : 0.0f;
        }

        floatx4 r;
        r.x = vals[0]; r.y = vals[1]; r.z = vals[2]; r.w = vals[3];
        __builtin_nontemporal_store(r, op + (size_t)k * (size_t)THREADS);
    }
}

extern "C" void kernel_launch(void* const* d_in, const int* in_sizes, int n_in,
                              void* d_out, int out_size, void* d_ws, size_t ws_size,
                              hipStream_t stream) {
    const float* spectrum    = (const float*)d_in[0];
    const float* pepmass     = (const float*)d_in[1];
    const float* prefix_mass = (const float*)d_in[2];
    const float* masses      = (const float*)d_in[3];
    const int*   direction   = (const int*)d_in[4];
    float* out = (float*)d_out;

    int batch = in_sizes[1];                // 32768
    intensity_kernel<<<GRID, BLOCK, 0, stream>>>(
        spectrum, pepmass, prefix_mass, masses, direction, out, batch);
}

// Round 2
// 284.461 us; speedup vs baseline: 1.2006x; 1.2006x over previous
//
#include <hip/hip_runtime.h>
#include <hip/hip_fp16.h>

// DeepNovo intensity-window gather, round 7.
// Ladder (kernel-time = dur_us - ~171us poison fill):
//   R5: LDS fp16 spectrum, BLOCK=640 (520 active), 2 blk/CU, 20 waves/CU = ~122us
//   R6: global L2 gathers @ 32 waves/CU = ~170us  (REGRESSION: scattered
//       global_load splits into ~30 cache-line segments/inst at the per-CU
//       TA -> ~1.6 TB/s cap. LDS gather is ~3x cheaper per wave-iter.)
// R7: back to LDS gathers, fix R5's occupancy instead.
//   - Column-invariance needs THREADS % 520 == 0 (520 = 8*5*13). Power-of-2
//     shapes can't divide it; BLOCK=960 (15 waves, factor 5) x GRID=494
//     (factor 13) = 474240 = 520*912. All lanes active (R5 wasted 120/640).
//   - 60KB LDS -> 2 blocks/CU: 30 waves/CU (vs R5's 20). 238 CUs get 2
//     blocks, 18 get 1 -> 3.6% imbalance only.
//   - __launch_bounds__(960,8) forces VGPR<=64: VGPR in (64,73] would drop
//     to 1 blk/CU (28-wave SIMD cap < 30) -- the cliff to avoid.
//   - pm/pf: direct global broadcast loads (L2-resident, ~1 line/wave;
//     proven cheap in R6). dir-select hoisted: su[j] = scy[j] ^ dir.
//   - unroll 2 (not 4): TLP from 30 waves replaces ILP, keeps VGPR < 64.
//   - flat chunk index = tid + k*THREADS -> stores contiguous grid-wide,
//     nontemporal float4.

#define MASS_H2O 18.01056f
#define MASS_NH3 17.02655f

typedef float floatx4 __attribute__((ext_vector_type(4)));

constexpr int MAX_MZ = 30000;
constexpr int WIN = 10;
constexpr int CPR = 520;                 // float4 chunks per batch row
constexpr int BLOCK = 960;               // 15 waves
constexpr int GRID  = 494;               // 960*494 = 474240 = 520*912
constexpr int THREADS = GRID * BLOCK;
constexpr int ROW_STEP = THREADS / CPR;  // 912 rows per k-step

__global__ __launch_bounds__(BLOCK, 8) void intensity_kernel(
    const float* __restrict__ spectrum,
    const float* __restrict__ pepmass,
    const float* __restrict__ prefix_mass,
    const float* __restrict__ masses,
    const int*   __restrict__ dir_p,
    float* __restrict__ out,
    int batch)
{
    __shared__ __half sspec[MAX_MZ];     // 60,000 B -> 2 blocks/CU

    // Stage spectrum fp32 -> fp16 into LDS (coalesced float2 loads).
    {
        const float2* sp2 = reinterpret_cast<const float2*>(spectrum);
        __half2* dst = reinterpret_cast<__half2*>(sspec);
        for (int i = threadIdx.x; i < MAX_MZ / 2; i += BLOCK) {
            float2 t = sp2[i];
            dst[i] = __floats2half2_rn(t.x, t.y);
        }
    }

    const int tid = (int)blockIdx.x * BLOCK + (int)threadIdx.x;

    // ---- loop-invariant decode (THREADS % 520 == 0 -> col fixed) ----
    const int col  = tid % CPR;
    const int row0 = tid / CPR;
    const int v = col / 20;
    const int q = col - v * 20;
    const float ms = masses[v];
    const float lm = (v > 2) ? 1.0f : 0.0f;
    const int dir = dir_p[0];

    bool  su[4];      // base = su ? u : t   (t = pf+ms, u = pm-t)
    float aj[4];      // -H2O / -NH3 / 0
    float mj10[4];    // mul*10: 5 for ++ ions else 10 (bit-exact vs ref)
    int   wj[4];      // window position 0..9
#pragma unroll
    for (int j = 0; j < 4; ++j) {
        int e   = 4 * q + j;
        int ion = e / 10;
        wj[j] = e - ion * 10;
        bool scy = (ion >= 4);
        su[j] = scy ^ (dir != 0);        // dir-select hoisted out of the loop
        int kk = ion & 3;
        aj[j]   = (kk == 1) ? -MASS_H2O : (kk == 2) ? -MASS_NH3 : 0.0f;
        mj10[j] = (kk == 3) ? 5.0f : 10.0f;
    }

    __syncthreads();

    const int n = (batch - row0 + ROW_STEP - 1) / ROW_STEP;   // 35 or 36
    floatx4* op = reinterpret_cast<floatx4*>(out) + tid;

    int row = row0;
#pragma unroll 2
    for (int k = 0; k < n; ++k, row += ROW_STEP) {
        // lanes of a wave share 1-2 rows -> 1-2 cache lines, L2-resident
        float pm = pepmass[row];
        float pf = prefix_mass[row];
        float t = pf + ms;               // exact reference arithmetic
        float u = pm - t;

        float vals[4];
#pragma unroll
        for (int j = 0; j < 4; ++j) {
            float base = su[j] ? u : t;                 // true select: bit-exact
            float f = (base + aj[j]) * mj10[j];         // ==(base+add)*mul*10 exactly
            int idx = (int)rintf(f) - (WIN / 2);        // v_rndne + v_cvt_i32
            bool valid = (unsigned)idx <= (unsigned)(MAX_MZ - WIN);
            int safe = valid ? idx : 0;
            float s = __half2float(sspec[safe + wj[j]]);
            vals[j] = valid ? s * lm : 0.0f;
        }

        floatx4 r;
        r.x = vals[0]; r.y = vals[1]; r.z = vals[2]; r.w = vals[3];
        __builtin_nontemporal_store(r, op + (size_t)k * (size_t)THREADS);
    }
}

extern "C" void kernel_launch(void* const* d_in, const int* in_sizes, int n_in,
                              void* d_out, int out_size, void* d_ws, size_t ws_size,
                              hipStream_t stream) {
    const float* spectrum    = (const float*)d_in[0];
    const float* pepmass     = (const float*)d_in[1];
    const float* prefix_mass = (const float*)d_in[2];
    const float* masses      = (const float*)d_in[3];
    const int*   direction   = (const int*)d_in[4];
    float* out = (float*)d_out;

    int batch = in_sizes[1];             // 32768
    intensity_kernel<<<GRID, BLOCK, 0, stream>>>(
        spectrum, pepmass, prefix_mass, masses, direction, out, batch);
}

// Round 3
// 274.200 us; speedup vs baseline: 1.2455x; 1.0374x over previous
//
#include <hip/hip_runtime.h>
#include <hip/hip_fp16.h>

// DeepNovo intensity-window gather, round 8.
// Ladder (kernel-time = dur_us - ~171us poison fill):
//   R5: LDS fp16 spectrum, 640thr (520 active), 20 waves/CU, nt stores = ~122us
//   R6: global L2 gathers, 32 waves/CU, nt stores = ~170us (TA segment cap)
//   R7: LDS gathers, 960thr all-active, 30 waves/CU, nt stores = ~113us
// R7 post-mortem: +50% waves -> only +8%. Latency-bound is arithmetically
// impossible at 30 waves x unroll2 (would need ~15k-cycle chains). We are
// pipe-capped ~260 cyc/wave-iter, and both R5/R7 sit at 2.2-2.4 TB/s store
// BW regardless of occupancy -- while the harness poison fill hits 6.3 TB/s
// on the SAME buffer with plain cached stores. Prime suspect: nontemporal
// flag (introduced in R5 bundled, never isolated) caps the write path.
// R8 = R7 with ONE change: plain cached float4 stores (no nt).
//   - If right: kernel ~113 -> ~55-75us (store BW 2.4 -> >=4.5 TB/s).
//   - If null: store path exonerated; next attack is LDS gather count via
//     ds_read2_b32 (4 consecutive halfwords -> <=3 dwords for 80% of lanes).

#define MASS_H2O 18.01056f
#define MASS_NH3 17.02655f

typedef float floatx4 __attribute__((ext_vector_type(4)));

constexpr int MAX_MZ = 30000;
constexpr int WIN = 10;
constexpr int CPR = 520;                 // float4 chunks per batch row
constexpr int BLOCK = 960;               // 15 waves
constexpr int GRID  = 494;               // 960*494 = 474240 = 520*912
constexpr int THREADS = GRID * BLOCK;
constexpr int ROW_STEP = THREADS / CPR;  // 912 rows per k-step

__global__ __launch_bounds__(BLOCK, 8) void intensity_kernel(
    const float* __restrict__ spectrum,
    const float* __restrict__ pepmass,
    const float* __restrict__ prefix_mass,
    const float* __restrict__ masses,
    const int*   __restrict__ dir_p,
    float* __restrict__ out,
    int batch)
{
    __shared__ __half sspec[MAX_MZ];     // 60,000 B -> 2 blocks/CU

    // Stage spectrum fp32 -> fp16 into LDS (coalesced float2 loads).
    {
        const float2* sp2 = reinterpret_cast<const float2*>(spectrum);
        __half2* dst = reinterpret_cast<__half2*>(sspec);
        for (int i = threadIdx.x; i < MAX_MZ / 2; i += BLOCK) {
            float2 t = sp2[i];
            dst[i] = __floats2half2_rn(t.x, t.y);
        }
    }

    const int tid = (int)blockIdx.x * BLOCK + (int)threadIdx.x;

    // ---- loop-invariant decode (THREADS % 520 == 0 -> col fixed) ----
    const int col  = tid % CPR;
    const int row0 = tid / CPR;
    const int v = col / 20;
    const int q = col - v * 20;
    const float ms = masses[v];
    const float lm = (v > 2) ? 1.0f : 0.0f;
    const int dir = dir_p[0];

    bool  su[4];      // base = su ? u : t   (t = pf+ms, u = pm-t)
    float aj[4];      // -H2O / -NH3 / 0
    float mj10[4];    // mul*10: 5 for ++ ions else 10 (bit-exact vs ref)
    int   wj[4];      // window position 0..9
#pragma unroll
    for (int j = 0; j < 4; ++j) {
        int e   = 4 * q + j;
        int ion = e / 10;
        wj[j] = e - ion * 10;
        bool scy = (ion >= 4);
        su[j] = scy ^ (dir != 0);        // dir-select hoisted out of the loop
        int kk = ion & 3;
        aj[j]   = (kk == 1) ? -MASS_H2O : (kk == 2) ? -MASS_NH3 : 0.0f;
        mj10[j] = (kk == 3) ? 5.0f : 10.0f;
    }

    __syncthreads();

    const int n = (batch - row0 + ROW_STEP - 1) / ROW_STEP;   // 35 or 36
    floatx4* op = reinterpret_cast<floatx4*>(out) + tid;

    int row = row0;
#pragma unroll 2
    for (int k = 0; k < n; ++k, row += ROW_STEP) {
        // lanes of a wave share 1-2 rows -> 1-2 cache lines, L2-resident
        float pm = pepmass[row];
        float pf = prefix_mass[row];
        float t = pf + ms;               // exact reference arithmetic
        float u = pm - t;

        float vals[4];
#pragma unroll
        for (int j = 0; j < 4; ++j) {
            float base = su[j] ? u : t;                 // true select: bit-exact
            float f = (base + aj[j]) * mj10[j];         // ==(base+add)*mul*10 exactly
            int idx = (int)rintf(f) - (WIN / 2);        // v_rndne + v_cvt_i32
            bool valid = (unsigned)idx <= (unsigned)(MAX_MZ - WIN);
            int safe = valid ? idx : 0;
            float s = __half2float(sspec[safe + wj[j]]);
            vals[j] = valid ? s * lm : 0.0f;
        }

        floatx4 r;
        r.x = vals[0]; r.y = vals[1]; r.z = vals[2]; r.w = vals[3];
        op[(size_t)k * (size_t)THREADS] = r;            // plain cached store
    }
}

extern "C" void kernel_launch(void* const* d_in, const int* in_sizes, int n_in,
                              void* d_out, int out_size, void* d_ws, size_t ws_size,
                              hipStream_t stream) {
    const float* spectrum    = (const float*)d_in[0];
    const float* pepmass     = (const float*)d_in[1];
    const float* prefix_mass = (const float*)d_in[2];
    const float* masses      = (const float*)d_in[3];
    const int*   direction   = (const int*)d_in[4];
    float* out = (float*)d_out;

    int batch = in_sizes[1];             // 32768
    intensity_kernel<<<GRID, BLOCK, 0, stream>>>(
        spectrum, pepmass, prefix_mass, masses, direction, out, batch);
}

// Round 4
// 273.073 us; speedup vs baseline: 1.2507x; 1.0041x over previous
//
#include <hip/hip_runtime.h>
#include <hip/hip_fp16.h>

// DeepNovo intensity-window gather, round 9.
// Ladder (kernel-time = dur_us - ~170us poison fill):
//   R5: LDS pm/pf + LDS gather, nt stores, 20 waves/CU, 120 idle lanes = ~122us
//   R6: all-global gathers = ~170us (TA segment cap on scattered global)
//   R7: LDS gather, global pm/pf in-loop, nt, 30 waves/CU = ~113us
//   R8: R7 with cached stores = ~109us  (nt exonerated: +4%)
// R8 post-mortem: no pipe above 15% (VALU 12%, LDS 13%, TA 2%, store 6%)
// yet per-wave-iter wall time ~7400cyc vs ~1200cyc chain -> queued on an
// un-modeled serializer. Candidate: vmcnt is a FIFO shared by loads AND
// stores. R7/R8 issue [store, load pm, load pf] per iter -> waiting for
// iter-k's pm with vmcnt(N) forces iter-(k-1)'s STORE to commit at L2
// (~300-500+ cyc under 30-wave contention) -> every iter of every wave
// serializes on store-ack. Explains R6 worst-case (gathers in same FIFO)
// and why occupancy barely helps (ack latency grows with contention).
// R9 = R8 + decouple: stage pm/pf rows in LDS (~0.9KB) so the hot loop's
// only VMEM op is the fire-and-forget store (zero in-loop vmcnt waits;
// gather waits are lgkmcnt, a different counter). Also unroll spectrum
// staging (was a serial load->wait->cvt->write chain, ~4-6us fixed).
// Predict: kernel ~55-70us -> dur_us ~220-245. Null (~270) kills the
// coupling theory -> next round bisects the fixed cost.

#define MASS_H2O 18.01056f
#define MASS_NH3 17.02655f

typedef float floatx4 __attribute__((ext_vector_type(4)));

constexpr int MAX_MZ = 30000;
constexpr int WIN = 10;
constexpr int CPR = 520;                 // float4 chunks per batch row
constexpr int BLOCK = 960;               // 15 waves
constexpr int GRID  = 494;               // 960*494 = 474240 = 520*912
constexpr int THREADS = GRID * BLOCK;
constexpr int ROW_STEP = THREADS / CPR;  // 912 rows per k-step
constexpr int KMAX = 37;                 // max k-iters bound (ceil(32768/912)+1)
constexpr int DROWS = 3;                 // distinct row0 values per block

__global__ __launch_bounds__(BLOCK, 8) void intensity_kernel(
    const float* __restrict__ spectrum,
    const float* __restrict__ pepmass,
    const float* __restrict__ prefix_mass,
    const float* __restrict__ masses,
    const int*   __restrict__ dir_p,
    float* __restrict__ out,
    int batch)
{
    __shared__ __half sspec[MAX_MZ];          // 60,000 B
    __shared__ float  spm[DROWS * KMAX];      // 444 B
    __shared__ float  spf[DROWS * KMAX];      // 444 B

    const int tid = (int)blockIdx.x * BLOCK + (int)threadIdx.x;
    const int blkR = ((int)blockIdx.x * BLOCK) / CPR;   // first row0 in block

    // ---- stage spectrum fp32 -> fp16 (unrolled: independent iterations) ----
    {
        const float2* sp2 = reinterpret_cast<const float2*>(spectrum);
        __half2* dst = reinterpret_cast<__half2*>(sspec);
#pragma unroll 4
        for (int i = threadIdx.x; i < MAX_MZ / 2; i += BLOCK) {
            float2 t = sp2[i];
            dst[i] = __floats2half2_rn(t.x, t.y);
        }
    }
    // ---- stage this block's pm/pf rows: r = blkR + d + k*ROW_STEP ----
    {
        int i = threadIdx.x;
        if (i < 2 * DROWS * KMAX) {
            int which = i >= DROWS * KMAX;        // 0 -> pm, 1 -> pf
            int e = which ? i - DROWS * KMAX : i;
            int d = e / KMAX;
            int k = e - d * KMAX;
            int r = blkR + d + k * ROW_STEP;
            float val = 0.0f;
            if (r < batch) val = which ? prefix_mass[r] : pepmass[r];
            if (which) spf[e] = val; else spm[e] = val;
        }
    }

    // ---- loop-invariant decode (THREADS % 520 == 0 -> col fixed) ----
    const int col  = tid % CPR;
    const int row0 = tid / CPR;
    const int doff = (row0 - blkR) * KMAX;    // LDS row-slot base for this thread
    const int v = col / 20;
    const int q = col - v * 20;
    const float ms = masses[v];
    const float lm = (v > 2) ? 1.0f : 0.0f;
    const int dir = dir_p[0];

    bool  su[4];      // base = su ? u : t   (t = pf+ms, u = pm-t)
    float aj[4];      // -H2O / -NH3 / 0
    float mj10[4];    // mul*10: 5 for ++ ions else 10 (bit-exact vs ref)
    int   wj[4];      // window position 0..9
#pragma unroll
    for (int j = 0; j < 4; ++j) {
        int e   = 4 * q + j;
        int ion = e / 10;
        wj[j] = e - ion * 10;
        bool scy = (ion >= 4);
        su[j] = scy ^ (dir != 0);        // dir-select hoisted out of the loop
        int kk = ion & 3;
        aj[j]   = (kk == 1) ? -MASS_H2O : (kk == 2) ? -MASS_NH3 : 0.0f;
        mj10[j] = (kk == 3) ? 5.0f : 10.0f;
    }

    __syncthreads();

    const int n = (batch - row0 + ROW_STEP - 1) / ROW_STEP;   // 35 or 36
    floatx4* op = reinterpret_cast<floatx4*>(out) + tid;

#pragma unroll 2
    for (int k = 0; k < n; ++k) {
        // LDS broadcast (1-2 distinct addrs per wave) -- no vmcnt in loop
        float pm = spm[doff + k];
        float pf = spf[doff + k];
        float t = pf + ms;               // exact reference arithmetic
        float u = pm - t;

        float vals[4];
#pragma unroll
        for (int j = 0; j < 4; ++j) {
            float base = su[j] ? u : t;                 // true select: bit-exact
            float f = (base + aj[j]) * mj10[j];         // ==(base+add)*mul*10 exactly
            int idx = (int)rintf(f) - (WIN / 2);        // v_rndne + v_cvt_i32
            bool valid = (unsigned)idx <= (unsigned)(MAX_MZ - WIN);
            int safe = valid ? idx : 0;
            float s = __half2float(sspec[safe + wj[j]]);
            vals[j] = valid ? s * lm : 0.0f;
        }

        floatx4 r;
        r.x = vals[0]; r.y = vals[1]; r.z = vals[2]; r.w = vals[3];
        op[(size_t)k * (size_t)THREADS] = r;            // fire-and-forget store
    }
}

extern "C" void kernel_launch(void* const* d_in, const int* in_sizes, int n_in,
                              void* d_out, int out_size, void* d_ws, size_t ws_size,
                              hipStream_t stream) {
    const float* spectrum    = (const float*)d_in[0];
    const float* pepmass     = (const float*)d_in[1];
    const float* prefix_mass = (const float*)d_in[2];
    const float* masses      = (const float*)d_in[3];
    const int*   direction   = (const int*)d_in[4];
    float* out = (float*)d_out;

    int batch = in_sizes[1];             // 32768
    intensity_kernel<<<GRID, BLOCK, 0, stream>>>(
        spectrum, pepmass, prefix_mass, masses, direction, out, batch);
}